// Round 1
// baseline (2389.341 us; speedup 1.0000x reference)
//
#include <hip/hip_runtime.h>

#define N_NODES 100000
#define N_EDGES 3200000
#define OUT_DIM 176
#define LN_EPS 1e-5f

// ---------------------------------------------------------------------------
// Copy emb (N,64) into out[:, 0:64] with float4 vectorization.
// out row stride 176 floats = 44 float4; 64 floats = 16 float4 per row.
__global__ __launch_bounds__(256) void copy_emb_kernel(
    const float* __restrict__ emb, float* __restrict__ out) {
  int t = blockIdx.x * blockDim.x + threadIdx.x;
  int total = N_NODES * 16;
  if (t < total) {
    int n = t >> 4, q = t & 15;
    const float4* src = (const float4*)emb;
    float4* dst = (float4*)out;
    dst[n * 44 + q] = src[n * 16 + q];
  }
}

// ---------------------------------------------------------------------------
// SpMM scatter: side[rows[e]] += vals[e] * ego[cols[e]], DIN components.
// One edge per DIN lanes (DIN=64: wave per edge; DIN=32: 2 edges per wave).
template <int DIN>
__global__ __launch_bounds__(256) void scatter_kernel(
    const float* __restrict__ ego, const int* __restrict__ rows,
    const int* __restrict__ cols, const float* __restrict__ vals,
    float* __restrict__ side) {
  constexpr int EPW = 64 / DIN;  // edges per wave
  const int lane = threadIdx.x & 63;
  const int sub = lane / DIN;
  const int comp = lane % DIN;
  const int wave = (blockIdx.x * blockDim.x + threadIdx.x) >> 6;
  const int nwaves = (gridDim.x * blockDim.x) >> 6;
  for (long base = (long)wave * EPW; base < N_EDGES; base += (long)nwaves * EPW) {
    const long e = base + sub;
    if (e < N_EDGES) {
      const int r = rows[e];
      const int c = cols[e];
      const float v = vals[e];
      atomicAdd(&side[(long)r * DIN + comp], v * ego[(long)c * DIN + comp]);
    }
  }
}

// ---------------------------------------------------------------------------
// Fused dense layer: per node n,
//   s  = LN(leaky_relu((ego+side) @ w1 + b1)) * g1 + be1
//   bi = LN(leaky_relu((ego*side) @ w2 + b2)) * g2 + be2
//   ego_out = s + bi  ; out[:, COL_OFF:COL_OFF+DOUT] = l2_normalize(ego_out)
// One wave per node; lane j < DOUT owns output component j; input components
// broadcast via __shfl; LN / l2 reductions via __shfl_xor over width DOUT.
template <int DIN, int DOUT, int COL_OFF>
__global__ __launch_bounds__(256) void dense_kernel(
    const float* __restrict__ ego, const float* __restrict__ side,
    const float* __restrict__ w1, const float* __restrict__ b1,
    const float* __restrict__ w2, const float* __restrict__ b2,
    const float* __restrict__ g1, const float* __restrict__ be1,
    const float* __restrict__ g2, const float* __restrict__ be2,
    float* __restrict__ ego_out, float* __restrict__ out) {
  __shared__ float w1s[DIN * DOUT], w2s[DIN * DOUT];
  __shared__ float b1s[DOUT], b2s[DOUT], g1s[DOUT], be1s[DOUT], g2s[DOUT],
      be2s[DOUT];
  for (int i = threadIdx.x; i < DIN * DOUT; i += blockDim.x) {
    w1s[i] = w1[i];
    w2s[i] = w2[i];
  }
  for (int i = threadIdx.x; i < DOUT; i += blockDim.x) {
    b1s[i] = b1[i];
    b2s[i] = b2[i];
    g1s[i] = g1[i];
    be1s[i] = be1[i];
    g2s[i] = g2[i];
    be2s[i] = be2[i];
  }
  __syncthreads();

  const int lane = threadIdx.x & 63;
  const int node = (blockIdx.x * blockDim.x + threadIdx.x) >> 6;
  if (node >= N_NODES) return;

  float e = 0.f, s = 0.f;
  if (lane < DIN) {
    e = ego[(long)node * DIN + lane];
    s = side[(long)node * DIN + lane];
  }
  const float xs = e + s;  // for s-branch
  const float xp = e * s;  // for bi-branch

  const int j = (lane < DOUT) ? lane : 0;  // clamped output column
  float acc1 = b1s[j];
  float acc2 = b2s[j];
#pragma unroll
  for (int i = 0; i < DIN; ++i) {
    const float xsi = __shfl(xs, i, 64);
    const float xpi = __shfl(xp, i, 64);
    acc1 += xsi * w1s[i * DOUT + j];
    acc2 += xpi * w2s[i * DOUT + j];
  }

  // leaky_relu (slope 0.01, jax.nn.leaky_relu default)
  float h1 = acc1 > 0.f ? acc1 : 0.01f * acc1;
  float h2 = acc2 > 0.f ? acc2 : 0.01f * acc2;

  // LayerNorm over DOUT lanes (groups of DOUT; lanes >= DOUT are garbage but
  // stay in their own shuffle groups and are never read back).
  float m1 = h1, m2 = h2;
#pragma unroll
  for (int mask = DOUT / 2; mask > 0; mask >>= 1) {
    m1 += __shfl_xor(m1, mask, DOUT);
    m2 += __shfl_xor(m2, mask, DOUT);
  }
  m1 *= (1.0f / DOUT);
  m2 *= (1.0f / DOUT);
  float d1 = h1 - m1, d2 = h2 - m2;
  float v1 = d1 * d1, v2 = d2 * d2;
#pragma unroll
  for (int mask = DOUT / 2; mask > 0; mask >>= 1) {
    v1 += __shfl_xor(v1, mask, DOUT);
    v2 += __shfl_xor(v2, mask, DOUT);
  }
  v1 *= (1.0f / DOUT);
  v2 *= (1.0f / DOUT);
  const float sv = d1 * rsqrtf(v1 + LN_EPS) * g1s[j] + be1s[j];
  const float bv = d2 * rsqrtf(v2 + LN_EPS) * g2s[j] + be2s[j];
  const float en = sv + bv;

  // l2 normalize for output slice
  float ss = en * en;
#pragma unroll
  for (int mask = DOUT / 2; mask > 0; mask >>= 1) {
    ss += __shfl_xor(ss, mask, DOUT);
  }
  const float nrm = sqrtf(ss);
  const float ov = en / fmaxf(nrm, 1e-12f);

  if (lane < DOUT) {
    ego_out[(long)node * DOUT + lane] = en;
    out[(long)node * OUT_DIM + COL_OFF + lane] = ov;
  }
}

// ---------------------------------------------------------------------------
extern "C" void kernel_launch(void* const* d_in, const int* in_sizes, int n_in,
                              void* d_out, int out_size, void* d_ws,
                              size_t ws_size, hipStream_t stream) {
  const float* emb = (const float*)d_in[0];
  const int* rows = (const int*)d_in[1];
  const int* cols = (const int*)d_in[2];
  const float* vals = (const float*)d_in[3];

  // Per-layer params: base 4 + 8*k, order w1,b1,w2,b2,g1,be1,g2,be2
  const float* P[3][8];
  for (int k = 0; k < 3; ++k)
    for (int p = 0; p < 8; ++p) P[k][p] = (const float*)d_in[4 + 8 * k + p];

  float* out = (float*)d_out;
  float* ws = (float*)d_ws;
  float* side = ws;                      // N*64
  float* ego1 = side + (long)N_NODES * 64;  // N*64
  float* ego2 = ego1 + (long)N_NODES * 64;  // N*32
  float* ego3 = ego2 + (long)N_NODES * 32;  // N*16

  const int SCATTER_BLOCKS = 4096;
  const int DENSE_BLOCKS = (N_NODES * 64 + 255) / 256;  // wave per node

  // out[:, 0:64] = emb
  copy_emb_kernel<<<(N_NODES * 16 + 255) / 256, 256, 0, stream>>>(emb, out);

  // ---- layer 0: 64 -> 64 ----
  hipMemsetAsync(side, 0, (size_t)N_NODES * 64 * sizeof(float), stream);
  scatter_kernel<64><<<SCATTER_BLOCKS, 256, 0, stream>>>(emb, rows, cols, vals,
                                                         side);
  dense_kernel<64, 64, 64><<<DENSE_BLOCKS, 256, 0, stream>>>(
      emb, side, P[0][0], P[0][1], P[0][2], P[0][3], P[0][4], P[0][5], P[0][6],
      P[0][7], ego1, out);

  // ---- layer 1: 64 -> 32 ----
  hipMemsetAsync(side, 0, (size_t)N_NODES * 64 * sizeof(float), stream);
  scatter_kernel<64><<<SCATTER_BLOCKS, 256, 0, stream>>>(ego1, rows, cols,
                                                         vals, side);
  dense_kernel<64, 32, 128><<<DENSE_BLOCKS, 256, 0, stream>>>(
      ego1, side, P[1][0], P[1][1], P[1][2], P[1][3], P[1][4], P[1][5],
      P[1][6], P[1][7], ego2, out);

  // ---- layer 2: 32 -> 16 ----
  hipMemsetAsync(side, 0, (size_t)N_NODES * 32 * sizeof(float), stream);
  scatter_kernel<32><<<SCATTER_BLOCKS, 256, 0, stream>>>(ego2, rows, cols,
                                                         vals, side);
  dense_kernel<32, 16, 160><<<DENSE_BLOCKS, 256, 0, stream>>>(
      ego2, side, P[2][0], P[2][1], P[2][2], P[2][3], P[2][4], P[2][5],
      P[2][6], P[2][7], ego3, out);
}

// Round 2
// 1256.735 us; speedup vs baseline: 1.9012x; 1.9012x over previous
//
#include <hip/hip_runtime.h>

#define N_NODES 100000
#define N_EDGES 3200000
#define OUT_DIM 176
#define LN_EPS 1e-5f
#define SCAN_NBLK ((N_NODES + 255) / 256)  // 391

// ---------------------------------------------------------------------------
// out[:, 0:64] = emb, float4-vectorized. Row stride 176 fl = 44 float4.
__global__ __launch_bounds__(256) void copy_emb_kernel(
    const float* __restrict__ emb, float* __restrict__ out) {
  int t = blockIdx.x * blockDim.x + threadIdx.x;
  if (t < N_NODES * 16) {
    int n = t >> 4, q = t & 15;
    ((float4*)out)[n * 44 + q] = ((const float4*)emb)[n * 16 + q];
  }
}

// ---------------------------------------------------------------------------
// CSR build: count -> scan(3 kernels) -> fill packed {col, val}
__global__ __launch_bounds__(256) void count_kernel(
    const int* __restrict__ rows, int* __restrict__ cnt) {
  int e = blockIdx.x * blockDim.x + threadIdx.x;
  if (e < N_EDGES) atomicAdd(&cnt[rows[e]], 1);
}

// per-256-chunk exclusive scan; writes chunk-local exclusive to row_ptr,
// chunk total to blockSums
__global__ __launch_bounds__(256) void scan1_kernel(
    const int* __restrict__ cnt, int* __restrict__ row_ptr,
    int* __restrict__ blockSums) {
  __shared__ int sh[256];
  int i = blockIdx.x * 256 + threadIdx.x;
  int v = (i < N_NODES) ? cnt[i] : 0;
  sh[threadIdx.x] = v;
  __syncthreads();
  for (int off = 1; off < 256; off <<= 1) {
    int t = (threadIdx.x >= off) ? sh[threadIdx.x - off] : 0;
    __syncthreads();
    sh[threadIdx.x] += t;
    __syncthreads();
  }
  if (i < N_NODES) row_ptr[i] = sh[threadIdx.x] - v;  // exclusive
  if (threadIdx.x == 255) blockSums[blockIdx.x] = sh[255];
}

// single-block exclusive scan of blockSums (391 entries, 512 threads)
__global__ __launch_bounds__(512) void scan2_kernel(int* __restrict__ bs) {
  __shared__ int sh[512];
  int v = (threadIdx.x < SCAN_NBLK) ? bs[threadIdx.x] : 0;
  sh[threadIdx.x] = v;
  __syncthreads();
  for (int off = 1; off < 512; off <<= 1) {
    int t = (threadIdx.x >= off) ? sh[threadIdx.x - off] : 0;
    __syncthreads();
    sh[threadIdx.x] += t;
    __syncthreads();
  }
  if (threadIdx.x < SCAN_NBLK) bs[threadIdx.x] = sh[threadIdx.x] - v;
}

// add block offsets; produce final row_ptr + cursor copy; row_ptr[N]=E
__global__ __launch_bounds__(256) void scan3_kernel(
    int* __restrict__ row_ptr, const int* __restrict__ bs,
    int* __restrict__ cursor) {
  int i = blockIdx.x * 256 + threadIdx.x;
  if (i < N_NODES) {
    int v = row_ptr[i] + bs[blockIdx.x];
    row_ptr[i] = v;
    cursor[i] = v;
  }
  if (i == 0) row_ptr[N_NODES] = N_EDGES;
}

__global__ __launch_bounds__(256) void fill_kernel(
    const int* __restrict__ rows, const int* __restrict__ cols,
    const float* __restrict__ vals, int* __restrict__ cursor,
    int2* __restrict__ packed) {
  int e = blockIdx.x * blockDim.x + threadIdx.x;
  if (e < N_EDGES) {
    int r = rows[e];
    int p = atomicAdd(&cursor[r], 1);
    packed[p] = make_int2(cols[e], __float_as_int(vals[e]));
  }
}

// ---------------------------------------------------------------------------
// Fused layer: gather-SpMM (CSR, no atomics) + dense + LN + l2norm.
// Wave handles 64/DIN nodes; lane = comp within node; shfl width DIN for
// broadcasts, width DOUT for LN/l2 reductions.
template <int DIN, int DOUT, int COL_OFF>
__global__ __launch_bounds__(256) void layer_kernel(
    const float* __restrict__ ego, const int* __restrict__ row_ptr,
    const int2* __restrict__ packed, const float* __restrict__ w1,
    const float* __restrict__ b1, const float* __restrict__ w2,
    const float* __restrict__ b2, const float* __restrict__ g1,
    const float* __restrict__ be1, const float* __restrict__ g2,
    const float* __restrict__ be2, float* __restrict__ ego_out,
    float* __restrict__ out) {
  __shared__ float w1s[DIN * DOUT], w2s[DIN * DOUT];
  __shared__ float b1s[DOUT], b2s[DOUT], g1s[DOUT], be1s[DOUT], g2s[DOUT],
      be2s[DOUT];
  for (int i = threadIdx.x; i < DIN * DOUT; i += blockDim.x) {
    w1s[i] = w1[i];
    w2s[i] = w2[i];
  }
  for (int i = threadIdx.x; i < DOUT; i += blockDim.x) {
    b1s[i] = b1[i];
    b2s[i] = b2[i];
    g1s[i] = g1[i];
    be1s[i] = be1[i];
    g2s[i] = g2[i];
    be2s[i] = be2[i];
  }
  __syncthreads();

  constexpr int NPW = 64 / DIN;  // nodes per wave
  const int lane = threadIdx.x & 63;
  const int comp = lane % DIN;
  const int sub = lane / DIN;
  const int wave = (blockIdx.x * blockDim.x + threadIdx.x) >> 6;
  const int node = wave * NPW + sub;
  if (node >= N_NODES) return;

  const int start = row_ptr[node];
  const int end = row_ptr[node + 1];

  // ---- gather SpMM: side[comp] = sum_e val_e * ego[col_e][comp] ----
  float side = 0.f;
  for (int base = start; base < end; base += DIN) {
    const int m_idx = base + comp;
    int2 m = make_int2(0, 0);
    if (m_idx < end) m = packed[m_idx];
    const int cnt = min(end - base, DIN);
    int it = 0;
    for (; it + 3 < cnt; it += 4) {
      const int c0 = __shfl(m.x, it + 0, DIN);
      const int c1 = __shfl(m.x, it + 1, DIN);
      const int c2 = __shfl(m.x, it + 2, DIN);
      const int c3 = __shfl(m.x, it + 3, DIN);
      const float v0 = __int_as_float(__shfl(m.y, it + 0, DIN));
      const float v1 = __int_as_float(__shfl(m.y, it + 1, DIN));
      const float v2 = __int_as_float(__shfl(m.y, it + 2, DIN));
      const float v3 = __int_as_float(__shfl(m.y, it + 3, DIN));
      const float e0 = ego[(long)c0 * DIN + comp];
      const float e1 = ego[(long)c1 * DIN + comp];
      const float e2 = ego[(long)c2 * DIN + comp];
      const float e3 = ego[(long)c3 * DIN + comp];
      side += v0 * e0;
      side += v1 * e1;
      side += v2 * e2;
      side += v3 * e3;
    }
    for (; it < cnt; ++it) {
      const int c = __shfl(m.x, it, DIN);
      const float v = __int_as_float(__shfl(m.y, it, DIN));
      side += v * ego[(long)c * DIN + comp];
    }
  }

  const float e = ego[(long)node * DIN + comp];
  const float xs = e + side;  // s-branch
  const float xp = e * side;  // bi-branch

  const int j = (comp < DOUT) ? comp : 0;
  float acc1 = b1s[j];
  float acc2 = b2s[j];
#pragma unroll
  for (int i = 0; i < DIN; ++i) {
    const float xsi = __shfl(xs, i, DIN);
    const float xpi = __shfl(xp, i, DIN);
    acc1 += xsi * w1s[i * DOUT + j];
    acc2 += xpi * w2s[i * DOUT + j];
  }

  float h1 = acc1 > 0.f ? acc1 : 0.01f * acc1;
  float h2 = acc2 > 0.f ? acc2 : 0.01f * acc2;

  // LayerNorm over DOUT-lane groups
  float m1 = h1, m2 = h2;
#pragma unroll
  for (int mask = DOUT / 2; mask > 0; mask >>= 1) {
    m1 += __shfl_xor(m1, mask, DOUT);
    m2 += __shfl_xor(m2, mask, DOUT);
  }
  m1 *= (1.0f / DOUT);
  m2 *= (1.0f / DOUT);
  float d1 = h1 - m1, d2 = h2 - m2;
  float v1 = d1 * d1, v2 = d2 * d2;
#pragma unroll
  for (int mask = DOUT / 2; mask > 0; mask >>= 1) {
    v1 += __shfl_xor(v1, mask, DOUT);
    v2 += __shfl_xor(v2, mask, DOUT);
  }
  v1 *= (1.0f / DOUT);
  v2 *= (1.0f / DOUT);
  const float sv = d1 * rsqrtf(v1 + LN_EPS) * g1s[j] + be1s[j];
  const float bv = d2 * rsqrtf(v2 + LN_EPS) * g2s[j] + be2s[j];
  const float en = sv + bv;

  // l2 normalize
  float ss = en * en;
#pragma unroll
  for (int mask = DOUT / 2; mask > 0; mask >>= 1) {
    ss += __shfl_xor(ss, mask, DOUT);
  }
  const float ov = en / fmaxf(sqrtf(ss), 1e-12f);

  if (comp < DOUT) {
    ego_out[(long)node * DOUT + comp] = en;
    out[(long)node * OUT_DIM + COL_OFF + comp] = ov;
  }
}

// ---------------------------------------------------------------------------
extern "C" void kernel_launch(void* const* d_in, const int* in_sizes, int n_in,
                              void* d_out, int out_size, void* d_ws,
                              size_t ws_size, hipStream_t stream) {
  const float* emb = (const float*)d_in[0];
  const int* rows = (const int*)d_in[1];
  const int* cols = (const int*)d_in[2];
  const float* vals = (const float*)d_in[3];

  const float* P[3][8];
  for (int k = 0; k < 3; ++k)
    for (int p = 0; p < 8; ++p) P[k][p] = (const float*)d_in[4 + 8 * k + p];

  float* out = (float*)d_out;

  // Workspace layout (16B-aligned first):
  char* ws = (char*)d_ws;
  int2* packed = (int2*)ws;                               // E * 8B = 25.6 MB
  float* ego1 = (float*)(ws + (size_t)N_EDGES * 8);       // N*64
  float* ego2 = ego1 + (size_t)N_NODES * 64;              // N*32
  float* ego3 = ego2 + (size_t)N_NODES * 32;              // N*16
  int* row_ptr = (int*)(ego3 + (size_t)N_NODES * 16);     // N+1
  int* cursor = row_ptr + (N_NODES + 1);                  // N
  int* cnt = cursor + N_NODES;                            // N
  int* blockSums = cnt + N_NODES;                         // 512

  // ---- CSR build (reused by all 3 layers) ----
  hipMemsetAsync(cnt, 0, (size_t)N_NODES * sizeof(int), stream);
  count_kernel<<<(N_EDGES + 255) / 256, 256, 0, stream>>>(rows, cnt);
  scan1_kernel<<<SCAN_NBLK, 256, 0, stream>>>(cnt, row_ptr, blockSums);
  scan2_kernel<<<1, 512, 0, stream>>>(blockSums);
  scan3_kernel<<<SCAN_NBLK, 256, 0, stream>>>(row_ptr, blockSums, cursor);
  fill_kernel<<<(N_EDGES + 255) / 256, 256, 0, stream>>>(rows, cols, vals,
                                                         cursor, packed);

  // out[:, 0:64] = emb
  copy_emb_kernel<<<(N_NODES * 16 + 255) / 256, 256, 0, stream>>>(emb, out);

  // ---- fused layers ----
  layer_kernel<64, 64, 64><<<(N_NODES * 64 + 255) / 256, 256, 0, stream>>>(
      emb, row_ptr, packed, P[0][0], P[0][1], P[0][2], P[0][3], P[0][4],
      P[0][5], P[0][6], P[0][7], ego1, out);
  layer_kernel<64, 32, 128><<<(N_NODES * 64 + 255) / 256, 256, 0, stream>>>(
      ego1, row_ptr, packed, P[1][0], P[1][1], P[1][2], P[1][3], P[1][4],
      P[1][5], P[1][6], P[1][7], ego2, out);
  layer_kernel<32, 16, 160><<<(N_NODES * 32 + 255) / 256, 256, 0, stream>>>(
      ego2, row_ptr, packed, P[2][0], P[2][1], P[2][2], P[2][3], P[2][4],
      P[2][5], P[2][6], P[2][7], ego3, out);
}

// Round 3
// 1203.539 us; speedup vs baseline: 1.9853x; 1.0442x over previous
//
#include <hip/hip_runtime.h>

#define N_NODES 100000
#define N_EDGES 3200000
#define OUT_DIM 176
#define LN_EPS 1e-5f
#define SCAN_NBLK ((N_NODES + 255) / 256)  // 391

// ---------------------------------------------------------------------------
// out[:, 0:64] = emb, float4-vectorized. Row stride 176 fl = 44 float4.
__global__ __launch_bounds__(256) void copy_emb_kernel(
    const float* __restrict__ emb, float* __restrict__ out) {
  int t = blockIdx.x * blockDim.x + threadIdx.x;
  if (t < N_NODES * 16) {
    int n = t >> 4, q = t & 15;
    ((float4*)out)[n * 44 + q] = ((const float4*)emb)[n * 16 + q];
  }
}

// ---------------------------------------------------------------------------
// CSR build: count -> scan(3 kernels) -> fill packed {col, val}
__global__ __launch_bounds__(256) void count_kernel(
    const int* __restrict__ rows, int* __restrict__ cnt) {
  int e = blockIdx.x * blockDim.x + threadIdx.x;
  if (e < N_EDGES) atomicAdd(&cnt[rows[e]], 1);
}

__global__ __launch_bounds__(256) void scan1_kernel(
    const int* __restrict__ cnt, int* __restrict__ row_ptr,
    int* __restrict__ blockSums) {
  __shared__ int sh[256];
  int i = blockIdx.x * 256 + threadIdx.x;
  int v = (i < N_NODES) ? cnt[i] : 0;
  sh[threadIdx.x] = v;
  __syncthreads();
  for (int off = 1; off < 256; off <<= 1) {
    int t = (threadIdx.x >= off) ? sh[threadIdx.x - off] : 0;
    __syncthreads();
    sh[threadIdx.x] += t;
    __syncthreads();
  }
  if (i < N_NODES) row_ptr[i] = sh[threadIdx.x] - v;  // exclusive
  if (threadIdx.x == 255) blockSums[blockIdx.x] = sh[255];
}

__global__ __launch_bounds__(512) void scan2_kernel(int* __restrict__ bs) {
  __shared__ int sh[512];
  int v = (threadIdx.x < SCAN_NBLK) ? bs[threadIdx.x] : 0;
  sh[threadIdx.x] = v;
  __syncthreads();
  for (int off = 1; off < 512; off <<= 1) {
    int t = (threadIdx.x >= off) ? sh[threadIdx.x - off] : 0;
    __syncthreads();
    sh[threadIdx.x] += t;
    __syncthreads();
  }
  if (threadIdx.x < SCAN_NBLK) bs[threadIdx.x] = sh[threadIdx.x] - v;
}

__global__ __launch_bounds__(256) void scan3_kernel(
    int* __restrict__ row_ptr, const int* __restrict__ bs,
    int* __restrict__ cursor) {
  int i = blockIdx.x * 256 + threadIdx.x;
  if (i < N_NODES) {
    int v = row_ptr[i] + bs[blockIdx.x];
    row_ptr[i] = v;
    cursor[i] = v;
  }
  if (i == 0) row_ptr[N_NODES] = N_EDGES;
}

__global__ __launch_bounds__(256) void fill_kernel(
    const int* __restrict__ rows, const int* __restrict__ cols,
    const float* __restrict__ vals, int* __restrict__ cursor,
    int2* __restrict__ packed) {
  int e = blockIdx.x * blockDim.x + threadIdx.x;
  if (e < N_EDGES) {
    int r = rows[e];
    int p = atomicAdd(&cursor[r], 1);
    packed[p] = make_int2(cols[e], __float_as_int(vals[e]));
  }
}

// ---------------------------------------------------------------------------
// Fused layer: gather-SpMM (CSR) + dense + LN + l2norm.
// One wave per node. LPE = DIN/4 lanes cover one edge-row with float4 loads;
// NGRP = 64/LPE edges are gathered concurrently (grp = lane/LPE).
// After gather, shfl_xor over masks LPE..32 folds group partials so every
// lane holds side[4*(lane%LPE) .. +3]. Dense phase broadcasts inputs with
// width-LPE shuffles; lane (lane%DOUT) owns output column; LN/l2 via
// width-DOUT shfl_xor (duplicate lane-groups compute identical values).
template <int DIN, int DOUT, int COL_OFF>
__global__ __launch_bounds__(512) void layer_kernel(
    const float* __restrict__ ego, const int* __restrict__ row_ptr,
    const int2* __restrict__ packed, const float* __restrict__ w1,
    const float* __restrict__ b1, const float* __restrict__ w2,
    const float* __restrict__ b2, const float* __restrict__ g1,
    const float* __restrict__ be1, const float* __restrict__ g2,
    const float* __restrict__ be2, float* __restrict__ ego_out,
    float* __restrict__ out) {
  constexpr int LPE = DIN / 4;   // lanes per edge-row (float4 each)
  constexpr int NGRP = 64 / LPE; // edges gathered concurrently

  __shared__ float w1s[DIN * DOUT], w2s[DIN * DOUT];
  __shared__ float b1s[DOUT], b2s[DOUT], g1s[DOUT], be1s[DOUT], g2s[DOUT],
      be2s[DOUT];
  for (int i = threadIdx.x; i < DIN * DOUT; i += blockDim.x) {
    w1s[i] = w1[i];
    w2s[i] = w2[i];
  }
  for (int i = threadIdx.x; i < DOUT; i += blockDim.x) {
    b1s[i] = b1[i];
    b2s[i] = b2[i];
    g1s[i] = g1[i];
    be1s[i] = be1[i];
    g2s[i] = g2[i];
    be2s[i] = be2[i];
  }
  __syncthreads();

  const int lane = threadIdx.x & 63;
  const int li = lane % LPE;   // float4 index within an edge-row
  const int grp = lane / LPE;  // which edge of the concurrent group
  const int node = (blockIdx.x * blockDim.x + threadIdx.x) >> 6;
  if (node >= N_NODES) return;

  const float4* __restrict__ ego4 = (const float4*)ego;
  const int start = row_ptr[node];
  const int end = row_ptr[node + 1];

  float4 side = make_float4(0.f, 0.f, 0.f, 0.f);
  for (int base = start; base < end; base += 64) {
    const int idx = base + lane;
    int2 m = make_int2(0, 0);  // col=0, val=0 padding: contributes 0
    if (idx < end) m = packed[idx];
    const int cnt = min(end - base, 64);
    const int kmax = (cnt + NGRP - 1) / NGRP;
    int k = 0;
    for (; k + 1 < kmax; k += 2) {
      const int s0 = k * NGRP + grp;
      const int s1 = s0 + NGRP;
      const int c0 = __shfl(m.x, s0, 64);
      const float v0 = __int_as_float(__shfl(m.y, s0, 64));
      const int c1 = __shfl(m.x, s1, 64);
      const float v1 = __int_as_float(__shfl(m.y, s1, 64));
      const float4 e0 = ego4[(long)c0 * LPE + li];
      const float4 e1 = ego4[(long)c1 * LPE + li];
      side.x += v0 * e0.x; side.y += v0 * e0.y;
      side.z += v0 * e0.z; side.w += v0 * e0.w;
      side.x += v1 * e1.x; side.y += v1 * e1.y;
      side.z += v1 * e1.z; side.w += v1 * e1.w;
    }
    if (k < kmax) {
      const int s0 = k * NGRP + grp;
      const int c0 = __shfl(m.x, s0, 64);
      const float v0 = __int_as_float(__shfl(m.y, s0, 64));
      const float4 e0 = ego4[(long)c0 * LPE + li];
      side.x += v0 * e0.x; side.y += v0 * e0.y;
      side.z += v0 * e0.z; side.w += v0 * e0.w;
    }
  }

  // fold the NGRP group partials: groups differ in lane bits >= log2(LPE)
#pragma unroll
  for (int mask = LPE; mask < 64; mask <<= 1) {
    side.x += __shfl_xor(side.x, mask, 64);
    side.y += __shfl_xor(side.y, mask, 64);
    side.z += __shfl_xor(side.z, mask, 64);
    side.w += __shfl_xor(side.w, mask, 64);
  }

  const float4 e4 = ego4[(long)node * LPE + li];
  float4 xs4, xp4;
  xs4.x = e4.x + side.x; xs4.y = e4.y + side.y;
  xs4.z = e4.z + side.z; xs4.w = e4.w + side.w;
  xp4.x = e4.x * side.x; xp4.y = e4.y * side.y;
  xp4.z = e4.z * side.z; xp4.w = e4.w * side.w;
  const float* xsa = (const float*)&xs4;
  const float* xpa = (const float*)&xp4;

  const int j = lane % DOUT;  // DOUT divides 64; duplicate groups identical
  float acc1 = b1s[j];
  float acc2 = b2s[j];
#pragma unroll
  for (int q = 0; q < LPE; ++q) {
#pragma unroll
    for (int r = 0; r < 4; ++r) {
      const int i = q * 4 + r;
      const float xsi = __shfl(xsa[r], q, LPE);
      const float xpi = __shfl(xpa[r], q, LPE);
      acc1 += xsi * w1s[i * DOUT + j];
      acc2 += xpi * w2s[i * DOUT + j];
    }
  }

  float h1 = acc1 > 0.f ? acc1 : 0.01f * acc1;
  float h2 = acc2 > 0.f ? acc2 : 0.01f * acc2;

  float m1 = h1, m2 = h2;
#pragma unroll
  for (int mask = DOUT / 2; mask > 0; mask >>= 1) {
    m1 += __shfl_xor(m1, mask, DOUT);
    m2 += __shfl_xor(m2, mask, DOUT);
  }
  m1 *= (1.0f / DOUT);
  m2 *= (1.0f / DOUT);
  float d1 = h1 - m1, d2 = h2 - m2;
  float v1 = d1 * d1, v2 = d2 * d2;
#pragma unroll
  for (int mask = DOUT / 2; mask > 0; mask >>= 1) {
    v1 += __shfl_xor(v1, mask, DOUT);
    v2 += __shfl_xor(v2, mask, DOUT);
  }
  v1 *= (1.0f / DOUT);
  v2 *= (1.0f / DOUT);
  const float sv = d1 * rsqrtf(v1 + LN_EPS) * g1s[j] + be1s[j];
  const float bv = d2 * rsqrtf(v2 + LN_EPS) * g2s[j] + be2s[j];
  const float en = sv + bv;

  float ss = en * en;
#pragma unroll
  for (int mask = DOUT / 2; mask > 0; mask >>= 1) {
    ss += __shfl_xor(ss, mask, DOUT);
  }
  const float ov = en / fmaxf(sqrtf(ss), 1e-12f);

  if (lane < DOUT) {
    ego_out[(long)node * DOUT + lane] = en;
    out[(long)node * OUT_DIM + COL_OFF + lane] = ov;
  }
}

// ---------------------------------------------------------------------------
extern "C" void kernel_launch(void* const* d_in, const int* in_sizes, int n_in,
                              void* d_out, int out_size, void* d_ws,
                              size_t ws_size, hipStream_t stream) {
  const float* emb = (const float*)d_in[0];
  const int* rows = (const int*)d_in[1];
  const int* cols = (const int*)d_in[2];
  const float* vals = (const float*)d_in[3];

  const float* P[3][8];
  for (int k = 0; k < 3; ++k)
    for (int p = 0; p < 8; ++p) P[k][p] = (const float*)d_in[4 + 8 * k + p];

  float* out = (float*)d_out;

  char* ws = (char*)d_ws;
  int2* packed = (int2*)ws;                            // E * 8B = 25.6 MB
  float* ego1 = (float*)(ws + (size_t)N_EDGES * 8);    // N*64 (16B aligned)
  float* ego2 = ego1 + (size_t)N_NODES * 64;           // N*32
  float* ego3 = ego2 + (size_t)N_NODES * 32;           // N*16
  int* row_ptr = (int*)(ego3 + (size_t)N_NODES * 16);  // N+1
  int* cursor = row_ptr + (N_NODES + 1);               // N
  int* cnt = cursor + N_NODES;                         // N
  int* blockSums = cnt + N_NODES;                      // 512

  // ---- CSR build (reused by all 3 layers) ----
  hipMemsetAsync(cnt, 0, (size_t)N_NODES * sizeof(int), stream);
  count_kernel<<<(N_EDGES + 255) / 256, 256, 0, stream>>>(rows, cnt);
  scan1_kernel<<<SCAN_NBLK, 256, 0, stream>>>(cnt, row_ptr, blockSums);
  scan2_kernel<<<1, 512, 0, stream>>>(blockSums);
  scan3_kernel<<<SCAN_NBLK, 256, 0, stream>>>(row_ptr, blockSums, cursor);
  fill_kernel<<<(N_EDGES + 255) / 256, 256, 0, stream>>>(rows, cols, vals,
                                                         cursor, packed);

  copy_emb_kernel<<<(N_NODES * 16 + 255) / 256, 256, 0, stream>>>(emb, out);

  // one wave per node, 512-thread blocks -> 8 nodes/block
  const int LAYER_BLOCKS = (N_NODES + 7) / 8;

  layer_kernel<64, 64, 64><<<LAYER_BLOCKS, 512, 0, stream>>>(
      emb, row_ptr, packed, P[0][0], P[0][1], P[0][2], P[0][3], P[0][4],
      P[0][5], P[0][6], P[0][7], ego1, out);
  layer_kernel<64, 32, 128><<<LAYER_BLOCKS, 512, 0, stream>>>(
      ego1, row_ptr, packed, P[1][0], P[1][1], P[1][2], P[1][3], P[1][4],
      P[1][5], P[1][6], P[1][7], ego2, out);
  layer_kernel<32, 16, 160><<<LAYER_BLOCKS, 512, 0, stream>>>(
      ego2, row_ptr, packed, P[2][0], P[2][1], P[2][2], P[2][3], P[2][4],
      P[2][5], P[2][6], P[2][7], ego3, out);
}